// Round 6
// baseline (444.189 us; speedup 1.0000x reference)
//
#include <hip/hip_runtime.h>
#include <cstdint>

#define B_ 2
#define N_ 50000
#define D_ 128
#define E_ 800000
#define TOK 100000   // B_*N_

typedef __bf16 bf16x8 __attribute__((ext_vector_type(8)));
typedef float f32x4 __attribute__((ext_vector_type(4)));

__device__ __forceinline__ unsigned short f2bf(float f) {
  union { float f; uint32_t u; } v; v.f = f;
  uint32_t u = v.u;
  return (unsigned short)((u + 0x7FFFu + ((u >> 16) & 1u)) >> 16);
}
__device__ __forceinline__ float uasf(uint32_t u) {
  union { uint32_t u; float f; } v; v.u = u; return v.f;
}

// ---------------- CSR build: histogram of edge_dst --------------------------
__global__ __launch_bounds__(256) void hist_k(const int* __restrict__ edst,
                                              int* __restrict__ cnt) {
  int e = blockIdx.x * 256 + threadIdx.x;
  if (e < E_) atomicAdd(&cnt[edst[e]], 1);
}

// ---------------- hierarchical scan: phase 1 (block-local) ------------------
__global__ __launch_bounds__(1024) void scan1_k(const int* __restrict__ cnt,
                                                int* __restrict__ part,
                                                int* __restrict__ bsum) {
  __shared__ int wsum[16], woff[16];
  const int tid = threadIdx.x, lane = tid & 63, wv = tid >> 6;
  int i = blockIdx.x * 1024 + tid;
  int v = (i < N_) ? cnt[i] : 0;
  int s = v;
#pragma unroll
  for (int off = 1; off < 64; off <<= 1) {
    int t = __shfl_up(s, off);
    if (lane >= off) s += t;
  }
  if (lane == 63) wsum[wv] = s;
  __syncthreads();
  if (tid == 0) {
    int a = 0;
#pragma unroll
    for (int w = 0; w < 16; ++w) { woff[w] = a; a += wsum[w]; }
    bsum[blockIdx.x] = a;
  }
  __syncthreads();
  if (i < N_) part[i] = woff[wv] + s - v;
}

// ---------------- phase 2: scan the 49 block sums (one wave) ----------------
__global__ __launch_bounds__(64) void scan2_k(const int* __restrict__ bsum,
                                              int* __restrict__ boff) {
  int lane = threadIdx.x;
  int v = (lane < 49) ? bsum[lane] : 0;
  int s = v;
#pragma unroll
  for (int off = 1; off < 64; off <<= 1) {
    int t = __shfl_up(s, off);
    if (lane >= off) s += t;
  }
  boff[lane] = s - v;
}

// ---------------- phase 3: add block offsets, write rs + cursor -------------
__global__ __launch_bounds__(1024) void scan3_k(const int* __restrict__ part,
                                                const int* __restrict__ boff,
                                                int* __restrict__ rs,
                                                int* __restrict__ cursor) {
  int i = blockIdx.x * 1024 + threadIdx.x;
  if (i < N_) {
    int v = part[i] + boff[blockIdx.x];
    rs[i] = v; cursor[i] = v;
  }
  if (i == 0) rs[N_] = E_;
}

// ---------------- CSR build: counting-sort edge srcs by dst -----------------
__global__ __launch_bounds__(256) void fill_k(const int* __restrict__ esrc,
                                              const int* __restrict__ edst,
                                              int* __restrict__ cursor,
                                              int* __restrict__ sorted_src) {
  int e = blockIdx.x * 256 + threadIdx.x;
  if (e < E_) {
    int pos = atomicAdd(&cursor[edst[e]], 1);
    sorted_src[pos] = esrc[e];
  }
}

// ---------------- x -> batch-interleaved bf16 rows xb[node][2][128] ---------
__global__ __launch_bounds__(256) void prep_x_k(const float* __restrict__ x,
                                                unsigned short* __restrict__ xb) {
  int q = (blockIdx.x * 256 + threadIdx.x) * 4;  // 0..12.8M, exact
  int node = q >> 8;
  int rem = q & 255;
  int b = rem >> 7, c = rem & 127;
  float4 v = *(const float4*)(x + (size_t)b * (N_ * D_) + node * 128 + c);
  uint2 p = { (uint32_t)f2bf(v.x) | ((uint32_t)f2bf(v.y) << 16),
              (uint32_t)f2bf(v.z) | ((uint32_t)f2bf(v.w) << 16) };
  *(uint2*)(xb + q) = p;
}

// ---------------- fused gather + dual LayerNorm -> h = [LN(x), LN(nb)] -----
// One wave per node; one 512B row-pair load per edge covers both batches.
__global__ __launch_bounds__(256) void gather_ln_k(
    const float* __restrict__ x, const unsigned short* __restrict__ xb,
    const int* __restrict__ rs, const int* __restrict__ ss,
    const float* __restrict__ sn_g, const float* __restrict__ sn_b,
    const float* __restrict__ nn_g, const float* __restrict__ nn_b,
    unsigned short* __restrict__ h) {
  const int node = blockIdx.x * 4 + (threadIdx.x >> 6);   // grid exact: 50000
  const int lane = threadIdx.x & 63;
  const int half = lane >> 5;        // batch index
  const int l32 = lane & 31;
  const int c = l32 * 4;
  const int r0 = rs[node], r1 = rs[node + 1];
  const unsigned short* xrow = xb + lane * 4;
  float a0 = 0.f, a1 = 0.f, a2 = 0.f, a3 = 0.f;
  for (int e = r0; e < r1; e += 8) {
#pragma unroll
    for (int j = 0; j < 8; ++j) {
      int ej = e + j;
      int idx = ss[(ej < r1) ? ej : r0];
      uint2 v = *(const uint2*)(xrow + (size_t)idx * 256);
      if (ej < r1) {
        a0 += uasf(v.x << 16); a1 += uasf(v.x & 0xffff0000u);
        a2 += uasf(v.y << 16); a3 += uasf(v.y & 0xffff0000u);
      }
    }
  }
  const float invd = 1.0f / fmaxf((float)(r1 - r0), 1.0f);
  float n0 = a0 * invd, n1 = a1 * invd, n2 = a2 * invd, n3 = a3 * invd;
  float4 xv = *(const float4*)(x + (size_t)half * (N_ * D_) + node * 128 + c);
  float sx = (xv.x + xv.y) + (xv.z + xv.w);
  float sxx = (xv.x * xv.x + xv.y * xv.y) + (xv.z * xv.z + xv.w * xv.w);
  float sn = (n0 + n1) + (n2 + n3);
  float snn = (n0 * n0 + n1 * n1) + (n2 * n2 + n3 * n3);
#pragma unroll
  for (int off = 1; off < 32; off <<= 1) {   // stays within the 32-lane half
    sx  += __shfl_xor(sx, off);  sxx += __shfl_xor(sxx, off);
    sn  += __shfl_xor(sn, off);  snn += __shfl_xor(snn, off);
  }
  const float r = 1.0f / 128.0f;
  float mx = sx * r, vx = fmaxf(sxx * r - mx * mx, 0.f);
  float mn = sn * r, vn = fmaxf(snn * r - mn * mn, 0.f);
  float rx = rsqrtf(vx + 1e-5f), rn = rsqrtf(vn + 1e-5f);
  float4 g1v = *(const float4*)(sn_g + c), b1v = *(const float4*)(sn_b + c);
  float4 g2v = *(const float4*)(nn_g + c), b2v = *(const float4*)(nn_b + c);
  float y0 = (xv.x - mx) * rx * g1v.x + b1v.x;
  float y1 = (xv.y - mx) * rx * g1v.y + b1v.y;
  float y2 = (xv.z - mx) * rx * g1v.z + b1v.z;
  float y3 = (xv.w - mx) * rx * g1v.w + b1v.w;
  float z0 = (n0 - mn) * rn * g2v.x + b2v.x;
  float z1 = (n1 - mn) * rn * g2v.y + b2v.y;
  float z2 = (n2 - mn) * rn * g2v.z + b2v.z;
  float z3 = (n3 - mn) * rn * g2v.w + b2v.w;
  unsigned short* hr = h + ((size_t)half * N_ + node) * 256;
  uint2 py = { (uint32_t)f2bf(y0) | ((uint32_t)f2bf(y1) << 16),
               (uint32_t)f2bf(y2) | ((uint32_t)f2bf(y3) << 16) };
  uint2 pz = { (uint32_t)f2bf(z0) | ((uint32_t)f2bf(z1) << 16),
               (uint32_t)f2bf(z2) | ((uint32_t)f2bf(z3) << 16) };
  *(uint2*)(hr + c)       = py;
  *(uint2*)(hr + 128 + c) = pz;
}

// ---------------- weight transpose to bf16 [n][k] ---------------------------
__global__ __launch_bounds__(256) void prep_w_k(
    const float* __restrict__ W1, const float* __restrict__ W2,
    unsigned short* __restrict__ W1t, unsigned short* __restrict__ W2t) {
  int t = blockIdx.x * 256 + threadIdx.x;
  if (t < 65536) {
    int n = t >> 8, k = t & 255;
    W1t[t] = f2bf(W1[k * 256 + n]);
  } else if (t < 65536 + 32768) {
    int t2 = t - 65536;
    int n = t2 >> 8, k = t2 & 255;
    W2t[t2] = f2bf(W2[k * 128 + n]);
  }
}

// ---------------- GEMM1: h1 = GELU(h @ W1t^T + b1), tile 128x256 ------------
__global__ __launch_bounds__(256, 2) void gemm1_k(
    const unsigned short* __restrict__ A,
    const unsigned short* __restrict__ Wt,
    const float* __restrict__ bias,
    unsigned short* __restrict__ outp, int M) {
  constexpr int LDA = 72;
  __shared__ unsigned short As[128 * LDA];
  __shared__ unsigned short Bs[256 * LDA];
  const int tid = threadIdx.x;
  const int wave = tid >> 6, lane = tid & 63;
  const int wr = wave >> 1, wc = wave & 1;   // wave: 64 rows x 128 cols
  const int quad = lane >> 4, l15 = lane & 15;
  const int m0 = blockIdx.x * 128;
  f32x4 acc[4][8] = {};
  for (int kb = 0; kb < 256; kb += 64) {
#pragma unroll
    for (int c = 0; c < 4; ++c) {            // A tile: 128 rows x 64 k
      int idx = c * 256 + tid;
      int row = idx >> 3, c8 = (idx & 7) << 3;
      int gm = m0 + row;
      uint4 va = {0u, 0u, 0u, 0u};
      if (gm < M) va = *(const uint4*)(A + (size_t)gm * 256 + kb + c8);
      *(uint4*)(&As[row * LDA + c8]) = va;
    }
#pragma unroll
    for (int c = 0; c < 8; ++c) {            // B tile: 256 rows x 64 k
      int idx = c * 256 + tid;
      int row = idx >> 3, c8 = (idx & 7) << 3;
      uint4 vb = *(const uint4*)(Wt + (size_t)row * 256 + kb + c8);
      *(uint4*)(&Bs[row * LDA + c8]) = vb;
    }
    __syncthreads();
#pragma unroll
    for (int kc = 0; kc < 64; kc += 32) {
      bf16x8 a[4], b[8];
#pragma unroll
      for (int i = 0; i < 4; ++i)
        a[i] = *(const bf16x8*)(&As[(wr * 64 + i * 16 + l15) * LDA + kc + quad * 8]);
#pragma unroll
      for (int i = 0; i < 8; ++i)
        b[i] = *(const bf16x8*)(&Bs[(wc * 128 + i * 16 + l15) * LDA + kc + quad * 8]);
#pragma unroll
      for (int mi = 0; mi < 4; ++mi)
#pragma unroll
        for (int ni = 0; ni < 8; ++ni)
          acc[mi][ni] = __builtin_amdgcn_mfma_f32_16x16x32_bf16(a[mi], b[ni], acc[mi][ni], 0, 0, 0);
    }
    __syncthreads();
  }
#pragma unroll
  for (int mi = 0; mi < 4; ++mi) {
#pragma unroll
    for (int ni = 0; ni < 8; ++ni) {
      int col = wc * 128 + ni * 16 + l15;
      float bv = bias[col];
#pragma unroll
      for (int rr = 0; rr < 4; ++rr) {
        int row = m0 + wr * 64 + mi * 16 + quad * 4 + rr;
        if (row < M) {
          float v = acc[mi][ni][rr] + bv;
          v = 0.5f * v * (1.0f + erff(v * 0.70710678118654752f));
          outp[(size_t)row * 256 + col] = f2bf(v);
        }
      }
    }
  }
}

// ---------------- GEMM2: out = h1 @ W2t^T + b2 + x (fp32 out) ---------------
__global__ __launch_bounds__(256, 2) void gemm2_k(
    const unsigned short* __restrict__ A,
    const unsigned short* __restrict__ Wt,
    const float* __restrict__ bias,
    const float* __restrict__ resid,
    float* __restrict__ outp, int M) {
  constexpr int LDA = 72;
  __shared__ unsigned short As[128 * LDA];
  __shared__ unsigned short Bs[128 * LDA];
  const int tid = threadIdx.x;
  const int wave = tid >> 6, lane = tid & 63;
  const int wr = wave >> 1, wc = wave & 1;
  const int quad = lane >> 4, l15 = lane & 15;
  const int m0 = blockIdx.x * 128;
  f32x4 acc[4][4] = {};
  for (int kb = 0; kb < 256; kb += 64) {
#pragma unroll
    for (int c = 0; c < 4; ++c) {
      int idx = c * 256 + tid;
      int row = idx >> 3, c8 = (idx & 7) << 3;
      int gm = m0 + row;
      uint4 va = {0u, 0u, 0u, 0u};
      if (gm < M) va = *(const uint4*)(A + (size_t)gm * 256 + kb + c8);
      *(uint4*)(&As[row * LDA + c8]) = va;
    }
#pragma unroll
    for (int c = 0; c < 4; ++c) {           // B tile: 128 rows x 64 k (1024 slots)
      int idx = c * 256 + tid;
      int row = idx >> 3, c8 = (idx & 7) << 3;
      uint4 vb = *(const uint4*)(Wt + (size_t)row * 256 + kb + c8);
      *(uint4*)(&Bs[row * LDA + c8]) = vb;
    }
    __syncthreads();
#pragma unroll
    for (int kc = 0; kc < 64; kc += 32) {
      bf16x8 a[4], b[4];
#pragma unroll
      for (int i = 0; i < 4; ++i) {
        a[i] = *(const bf16x8*)(&As[(wr * 64 + i * 16 + l15) * LDA + kc + quad * 8]);
        b[i] = *(const bf16x8*)(&Bs[(wc * 64 + i * 16 + l15) * LDA + kc + quad * 8]);
      }
#pragma unroll
      for (int mi = 0; mi < 4; ++mi)
#pragma unroll
        for (int ni = 0; ni < 4; ++ni)
          acc[mi][ni] = __builtin_amdgcn_mfma_f32_16x16x32_bf16(a[mi], b[ni], acc[mi][ni], 0, 0, 0);
    }
    __syncthreads();
  }
#pragma unroll
  for (int mi = 0; mi < 4; ++mi) {
#pragma unroll
    for (int ni = 0; ni < 4; ++ni) {
      int col = wc * 64 + ni * 16 + l15;
      float bv = bias[col];
#pragma unroll
      for (int rr = 0; rr < 4; ++rr) {
        int row = m0 + wr * 64 + mi * 16 + quad * 4 + rr;
        if (row < M) {
          float v = acc[mi][ni][rr] + bv + resid[(size_t)row * 128 + col];
          outp[(size_t)row * 128 + col] = v;
        }
      }
    }
  }
}

extern "C" void kernel_launch(void* const* d_in, const int* in_sizes, int n_in,
                              void* d_out, int out_size, void* d_ws, size_t ws_size,
                              hipStream_t stream) {
  const float* x    = (const float*)d_in[0];
  const int* esrc   = (const int*)d_in[1];
  const int* edst   = (const int*)d_in[2];
  const float* sn_g = (const float*)d_in[4];
  const float* sn_b = (const float*)d_in[5];
  const float* nn_g = (const float*)d_in[6];
  const float* nn_b = (const float*)d_in[7];
  const float* W1   = (const float*)d_in[8];
  const float* b1   = (const float*)d_in[9];
  const float* W2   = (const float*)d_in[10];
  const float* b2   = (const float*)d_in[11];

  char* ws = (char*)d_ws;
  const size_t H_BYTES = (size_t)TOK * 256 * 2;          // 51.2 MB
  unsigned short* h = (unsigned short*)ws;               // [TOK][256] bf16
  // CSR + xb region (dead before gemm1), aliased by h1:
  char* csr = ws + H_BYTES;
  int* cnt        = (int*)(csr);                          // 50000 ints
  int* part       = (int*)(csr + 200000);                 // 50000 ints
  int* rs         = (int*)(csr + 400000);                 // 50001 ints
  int* cursor     = (int*)(csr + 600016);                 // 50000 ints
  int* bsum       = (int*)(csr + 800016);                 // 49 ints
  int* boff       = (int*)(csr + 800224);                 // 64 ints
  int* sorted_src = (int*)(csr + 800512);                 // 800000 ints -> ends 4,000,512
  unsigned short* xb = (unsigned short*)(csr + 4194304);  // [N][2][128] bf16, 25.6 MB
  unsigned short* h1 = (unsigned short*)(ws + H_BYTES);   // aliases CSR+xb after gather
  unsigned short* W1t = (unsigned short*)(ws + 2 * H_BYTES);
  unsigned short* W2t = W1t + 65536;

  hipMemsetAsync(cnt, 0, (size_t)N_ * sizeof(int), stream);
  prep_w_k<<<(98304 + 255) / 256, 256, 0, stream>>>(W1, W2, W1t, W2t);
  prep_x_k<<<12500, 256, 0, stream>>>(x, xb);
  hist_k<<<(E_ + 255) / 256, 256, 0, stream>>>(edst, cnt);
  scan1_k<<<49, 1024, 0, stream>>>(cnt, part, bsum);
  scan2_k<<<1, 64, 0, stream>>>(bsum, boff);
  scan3_k<<<49, 1024, 0, stream>>>(part, boff, rs, cursor);
  fill_k<<<(E_ + 255) / 256, 256, 0, stream>>>(esrc, edst, cursor, sorted_src);
  gather_ln_k<<<N_ / 4, 256, 0, stream>>>(x, xb, rs, sorted_src,
                                          sn_g, sn_b, nn_g, nn_b, h);
  gemm1_k<<<(TOK + 127) / 128, 256, 0, stream>>>(h, W1t, b1, h1, TOK);
  gemm2_k<<<(TOK + 127) / 128, 256, 0, stream>>>(h1, W2t, b2, x, (float*)d_out, TOK);
}

// Round 7
// 382.368 us; speedup vs baseline: 1.1617x; 1.1617x over previous
//
#include <hip/hip_runtime.h>
#include <cstdint>

#define B_ 2
#define N_ 50000
#define D_ 128
#define E_ 800000
#define TOK 100000   // B_*N_

typedef __bf16 bf16x8 __attribute__((ext_vector_type(8)));
typedef float f32x4 __attribute__((ext_vector_type(4)));

__device__ __forceinline__ unsigned short f2bf(float f) {
  union { float f; uint32_t u; } v; v.f = f;
  uint32_t u = v.u;
  return (unsigned short)((u + 0x7FFFu + ((u >> 16) & 1u)) >> 16);
}
__device__ __forceinline__ float uasf(uint32_t u) {
  union { uint32_t u; float f; } v; v.u = u; return v.f;
}

// ---- fused prep: xb build (blocks 0..12499), W transpose (12500..12883),
// ---- dst histogram (12884..16008) ------------------------------------------
__global__ __launch_bounds__(256) void prep_k(
    const float* __restrict__ x, const float* __restrict__ W1,
    const float* __restrict__ W2, const int* __restrict__ edst,
    unsigned short* __restrict__ xb, unsigned short* __restrict__ W1t,
    unsigned short* __restrict__ W2t, int* __restrict__ cnt) {
  const int blk = blockIdx.x;
  if (blk < 12500) {               // x -> batch-interleaved bf16 xb[node][2][128]
    int q = (blk * 256 + threadIdx.x) * 4;
    int node = q >> 8;
    int rem = q & 255;
    int b = rem >> 7, c = rem & 127;
    float4 v = *(const float4*)(x + (size_t)b * (N_ * D_) + node * 128 + c);
    uint2 p = { (uint32_t)f2bf(v.x) | ((uint32_t)f2bf(v.y) << 16),
                (uint32_t)f2bf(v.z) | ((uint32_t)f2bf(v.w) << 16) };
    *(uint2*)(xb + q) = p;
  } else if (blk < 12884) {        // weight transpose to bf16 [n][k]
    int t = (blk - 12500) * 256 + threadIdx.x;
    if (t < 65536) {
      int n = t >> 8, k = t & 255;
      W1t[t] = f2bf(W1[k * 256 + n]);
    } else {
      int t2 = t - 65536;
      int n = t2 >> 8, k = t2 & 255;
      W2t[t2] = f2bf(W2[k * 128 + n]);
    }
  } else {                         // histogram of edge_dst
    int e = (blk - 12884) * 256 + threadIdx.x;
    if (e < E_) atomicAdd(&cnt[edst[e]], 1);
  }
}

// ---------------- hierarchical scan: phase 1 (block-local) ------------------
__global__ __launch_bounds__(1024) void scan1_k(const int* __restrict__ cnt,
                                                int* __restrict__ part,
                                                int* __restrict__ bsum) {
  __shared__ int wsum[16], woff[16];
  const int tid = threadIdx.x, lane = tid & 63, wv = tid >> 6;
  int i = blockIdx.x * 1024 + tid;
  int v = (i < N_) ? cnt[i] : 0;
  int s = v;
#pragma unroll
  for (int off = 1; off < 64; off <<= 1) {
    int t = __shfl_up(s, off);
    if (lane >= off) s += t;
  }
  if (lane == 63) wsum[wv] = s;
  __syncthreads();
  if (tid == 0) {
    int a = 0;
#pragma unroll
    for (int w = 0; w < 16; ++w) { woff[w] = a; a += wsum[w]; }
    bsum[blockIdx.x] = a;
  }
  __syncthreads();
  if (i < N_) part[i] = woff[wv] + s - v;
}

// ---------------- phase 2: scan the 49 block sums (one wave) ----------------
__global__ __launch_bounds__(64) void scan2_k(const int* __restrict__ bsum,
                                              int* __restrict__ boff) {
  int lane = threadIdx.x;
  int v = (lane < 49) ? bsum[lane] : 0;
  int s = v;
#pragma unroll
  for (int off = 1; off < 64; off <<= 1) {
    int t = __shfl_up(s, off);
    if (lane >= off) s += t;
  }
  boff[lane] = s - v;
}

// ---------------- phase 3: add block offsets, write rs + cursor -------------
__global__ __launch_bounds__(1024) void scan3_k(const int* __restrict__ part,
                                                const int* __restrict__ boff,
                                                int* __restrict__ rs,
                                                int* __restrict__ cursor) {
  int i = blockIdx.x * 1024 + threadIdx.x;
  if (i < N_) {
    int v = part[i] + boff[blockIdx.x];
    rs[i] = v; cursor[i] = v;
  }
  if (i == 0) rs[N_] = E_;
}

// ---------------- CSR build: counting-sort edge srcs by dst -----------------
__global__ __launch_bounds__(256) void fill_k(const int* __restrict__ esrc,
                                              const int* __restrict__ edst,
                                              int* __restrict__ cursor,
                                              int* __restrict__ sorted_src) {
  int e = blockIdx.x * 256 + threadIdx.x;
  if (e < E_) {
    int pos = atomicAdd(&cursor[edst[e]], 1);
    sorted_src[pos] = esrc[e];
  }
}

// ---------------- fused gather + dual LayerNorm -> h = [LN(x), LN(nb)] -----
// One wave per node; one 512B row-pair load per edge covers both batches.
// 16-wide load batching (avg degree 16) for MLP.
__global__ __launch_bounds__(256) void gather_ln_k(
    const unsigned short* __restrict__ xb,
    const int* __restrict__ rs, const int* __restrict__ ss,
    const float* __restrict__ sn_g, const float* __restrict__ sn_b,
    const float* __restrict__ nn_g, const float* __restrict__ nn_b,
    unsigned short* __restrict__ h) {
  const int node = blockIdx.x * 4 + (threadIdx.x >> 6);   // grid exact: 50000
  const int lane = threadIdx.x & 63;
  const int half = lane >> 5;        // batch index
  const int l32 = lane & 31;
  const int c = l32 * 4;
  const int r0 = rs[node], r1 = rs[node + 1];
  const unsigned short* xrow = xb + lane * 4;
  float a0 = 0.f, a1 = 0.f, a2 = 0.f, a3 = 0.f;
  for (int e = r0; e < r1; e += 16) {
    int idx[16];
#pragma unroll
    for (int j = 0; j < 16; ++j) {
      int ej = e + j;
      idx[j] = ss[(ej < r1) ? ej : r0];
    }
    uint2 v[16];
#pragma unroll
    for (int j = 0; j < 16; ++j)
      v[j] = *(const uint2*)(xrow + (size_t)idx[j] * 256);
#pragma unroll
    for (int j = 0; j < 16; ++j) {
      if (e + j < r1) {
        a0 += uasf(v[j].x << 16); a1 += uasf(v[j].x & 0xffff0000u);
        a2 += uasf(v[j].y << 16); a3 += uasf(v[j].y & 0xffff0000u);
      }
    }
  }
  const float invd = 1.0f / fmaxf((float)(r1 - r0), 1.0f);
  float n0 = a0 * invd, n1 = a1 * invd, n2 = a2 * invd, n3 = a3 * invd;
  uint2 xq = *(const uint2*)(xrow + (size_t)node * 256);  // own row (bf16)
  float x0 = uasf(xq.x << 16), x1 = uasf(xq.x & 0xffff0000u);
  float x2 = uasf(xq.y << 16), x3 = uasf(xq.y & 0xffff0000u);
  float sx = (x0 + x1) + (x2 + x3);
  float sxx = (x0 * x0 + x1 * x1) + (x2 * x2 + x3 * x3);
  float sn = (n0 + n1) + (n2 + n3);
  float snn = (n0 * n0 + n1 * n1) + (n2 * n2 + n3 * n3);
#pragma unroll
  for (int off = 1; off < 32; off <<= 1) {   // stays within the 32-lane half
    sx  += __shfl_xor(sx, off);  sxx += __shfl_xor(sxx, off);
    sn  += __shfl_xor(sn, off);  snn += __shfl_xor(snn, off);
  }
  const float r = 1.0f / 128.0f;
  float mx = sx * r, vx = fmaxf(sxx * r - mx * mx, 0.f);
  float mn = sn * r, vn = fmaxf(snn * r - mn * mn, 0.f);
  float rx = rsqrtf(vx + 1e-5f), rn = rsqrtf(vn + 1e-5f);
  float4 g1v = *(const float4*)(sn_g + c), b1v = *(const float4*)(sn_b + c);
  float4 g2v = *(const float4*)(nn_g + c), b2v = *(const float4*)(nn_b + c);
  float y0 = (x0 - mx) * rx * g1v.x + b1v.x;
  float y1 = (x1 - mx) * rx * g1v.y + b1v.y;
  float y2 = (x2 - mx) * rx * g1v.z + b1v.z;
  float y3 = (x3 - mx) * rx * g1v.w + b1v.w;
  float z0 = (n0 - mn) * rn * g2v.x + b2v.x;
  float z1 = (n1 - mn) * rn * g2v.y + b2v.y;
  float z2 = (n2 - mn) * rn * g2v.z + b2v.z;
  float z3 = (n3 - mn) * rn * g2v.w + b2v.w;
  unsigned short* hr = h + ((size_t)half * N_ + node) * 256;
  uint2 py = { (uint32_t)f2bf(y0) | ((uint32_t)f2bf(y1) << 16),
               (uint32_t)f2bf(y2) | ((uint32_t)f2bf(y3) << 16) };
  uint2 pz = { (uint32_t)f2bf(z0) | ((uint32_t)f2bf(z1) << 16),
               (uint32_t)f2bf(z2) | ((uint32_t)f2bf(z3) << 16) };
  *(uint2*)(hr + c)       = py;
  *(uint2*)(hr + 128 + c) = pz;
}

// ---------------- GEMM1: h1 = GELU(h @ W1t^T + b1), tile 128x128 (y=2) ------
__global__ __launch_bounds__(256, 2) void gemm1_k(
    const unsigned short* __restrict__ A,
    const unsigned short* __restrict__ Wt,
    const float* __restrict__ bias,
    unsigned short* __restrict__ outp, int M) {
  constexpr int LDA = 72;
  __shared__ unsigned short As[128 * LDA];
  __shared__ unsigned short Bs[128 * LDA];
  const int tid = threadIdx.x;
  const int wave = tid >> 6, lane = tid & 63;
  const int wr = wave >> 1, wc = wave & 1;
  const int quad = lane >> 4, l15 = lane & 15;
  const int m0 = blockIdx.x * 128, n0 = blockIdx.y * 128;
  f32x4 acc[4][4] = {};
  for (int kb = 0; kb < 256; kb += 64) {
#pragma unroll
    for (int c = 0; c < 4; ++c) {
      int idx = c * 256 + tid;
      int row = idx >> 3, c8 = (idx & 7) << 3;
      int gm = m0 + row;
      uint4 va = {0u, 0u, 0u, 0u};
      if (gm < M) va = *(const uint4*)(A + (size_t)gm * 256 + kb + c8);
      *(uint4*)(&As[row * LDA + c8]) = va;
      uint4 vb = *(const uint4*)(Wt + (size_t)(n0 + row) * 256 + kb + c8);
      *(uint4*)(&Bs[row * LDA + c8]) = vb;
    }
    __syncthreads();
#pragma unroll
    for (int kc = 0; kc < 64; kc += 32) {
      bf16x8 a[4], b[4];
#pragma unroll
      for (int i = 0; i < 4; ++i) {
        a[i] = *(const bf16x8*)(&As[(wr * 64 + i * 16 + l15) * LDA + kc + quad * 8]);
        b[i] = *(const bf16x8*)(&Bs[(wc * 64 + i * 16 + l15) * LDA + kc + quad * 8]);
      }
#pragma unroll
      for (int mi = 0; mi < 4; ++mi)
#pragma unroll
        for (int ni = 0; ni < 4; ++ni)
          acc[mi][ni] = __builtin_amdgcn_mfma_f32_16x16x32_bf16(a[mi], b[ni], acc[mi][ni], 0, 0, 0);
    }
    __syncthreads();
  }
#pragma unroll
  for (int mi = 0; mi < 4; ++mi) {
#pragma unroll
    for (int ni = 0; ni < 4; ++ni) {
      int col = n0 + wc * 64 + ni * 16 + l15;
      float bv = bias[col];
#pragma unroll
      for (int rr = 0; rr < 4; ++rr) {
        int row = m0 + wr * 64 + mi * 16 + quad * 4 + rr;
        if (row < M) {
          float v = acc[mi][ni][rr] + bv;
          v = 0.5f * v * (1.0f + erff(v * 0.70710678118654752f));
          outp[(size_t)row * 256 + col] = f2bf(v);
        }
      }
    }
  }
}

// ---------------- GEMM2: out = h1 @ W2t^T + b2 + x (fp32 out) ---------------
__global__ __launch_bounds__(256, 2) void gemm2_k(
    const unsigned short* __restrict__ A,
    const unsigned short* __restrict__ Wt,
    const float* __restrict__ bias,
    const float* __restrict__ resid,
    float* __restrict__ outp, int M) {
  constexpr int LDA = 72;
  __shared__ unsigned short As[128 * LDA];
  __shared__ unsigned short Bs[128 * LDA];
  const int tid = threadIdx.x;
  const int wave = tid >> 6, lane = tid & 63;
  const int wr = wave >> 1, wc = wave & 1;
  const int quad = lane >> 4, l15 = lane & 15;
  const int m0 = blockIdx.x * 128;
  f32x4 acc[4][4] = {};
  for (int kb = 0; kb < 256; kb += 64) {
#pragma unroll
    for (int c = 0; c < 4; ++c) {
      int idx = c * 256 + tid;
      int row = idx >> 3, c8 = (idx & 7) << 3;
      int gm = m0 + row;
      uint4 va = {0u, 0u, 0u, 0u};
      if (gm < M) va = *(const uint4*)(A + (size_t)gm * 256 + kb + c8);
      *(uint4*)(&As[row * LDA + c8]) = va;
      uint4 vb = *(const uint4*)(Wt + (size_t)row * 256 + kb + c8);
      *(uint4*)(&Bs[row * LDA + c8]) = vb;
    }
    __syncthreads();
#pragma unroll
    for (int kc = 0; kc < 64; kc += 32) {
      bf16x8 a[4], b[4];
#pragma unroll
      for (int i = 0; i < 4; ++i) {
        a[i] = *(const bf16x8*)(&As[(wr * 64 + i * 16 + l15) * LDA + kc + quad * 8]);
        b[i] = *(const bf16x8*)(&Bs[(wc * 64 + i * 16 + l15) * LDA + kc + quad * 8]);
      }
#pragma unroll
      for (int mi = 0; mi < 4; ++mi)
#pragma unroll
        for (int ni = 0; ni < 4; ++ni)
          acc[mi][ni] = __builtin_amdgcn_mfma_f32_16x16x32_bf16(a[mi], b[ni], acc[mi][ni], 0, 0, 0);
    }
    __syncthreads();
  }
#pragma unroll
  for (int mi = 0; mi < 4; ++mi) {
#pragma unroll
    for (int ni = 0; ni < 4; ++ni) {
      int col = wc * 64 + ni * 16 + l15;
      float bv = bias[col];
#pragma unroll
      for (int rr = 0; rr < 4; ++rr) {
        int row = m0 + wr * 64 + mi * 16 + quad * 4 + rr;
        if (row < M) {
          float v = acc[mi][ni][rr] + bv + resid[(size_t)row * 128 + col];
          outp[(size_t)row * 128 + col] = v;
        }
      }
    }
  }
}

extern "C" void kernel_launch(void* const* d_in, const int* in_sizes, int n_in,
                              void* d_out, int out_size, void* d_ws, size_t ws_size,
                              hipStream_t stream) {
  const float* x    = (const float*)d_in[0];
  const int* esrc   = (const int*)d_in[1];
  const int* edst   = (const int*)d_in[2];
  const float* sn_g = (const float*)d_in[4];
  const float* sn_b = (const float*)d_in[5];
  const float* nn_g = (const float*)d_in[6];
  const float* nn_b = (const float*)d_in[7];
  const float* W1   = (const float*)d_in[8];
  const float* b1   = (const float*)d_in[9];
  const float* W2   = (const float*)d_in[10];
  const float* b2   = (const float*)d_in[11];

  char* ws = (char*)d_ws;
  const size_t H_BYTES = (size_t)TOK * 256 * 2;          // 51.2 MB
  unsigned short* h = (unsigned short*)ws;               // [TOK][256] bf16
  // CSR + xb region (dead before gemm1), aliased by h1:
  char* csr = ws + H_BYTES;
  int* cnt        = (int*)(csr);                          // 50000 ints
  int* part       = (int*)(csr + 200000);                 // 50000 ints
  int* rs         = (int*)(csr + 400000);                 // 50001 ints
  int* cursor     = (int*)(csr + 600016);                 // 50000 ints
  int* bsum       = (int*)(csr + 800016);                 // 49 ints
  int* boff       = (int*)(csr + 800224);                 // 64 ints
  int* sorted_src = (int*)(csr + 800512);                 // 800000 ints -> ends 4,000,512
  unsigned short* xb = (unsigned short*)(csr + 4194304);  // [N][2][128] bf16, 25.6 MB
  unsigned short* h1 = (unsigned short*)(ws + H_BYTES);   // aliases CSR+xb after gather
  unsigned short* W1t = (unsigned short*)(ws + 2 * H_BYTES);
  unsigned short* W2t = W1t + 65536;

  hipMemsetAsync(cnt, 0, (size_t)N_ * sizeof(int), stream);
  prep_k<<<16009, 256, 0, stream>>>(x, W1, W2, edst, xb, W1t, W2t, cnt);
  scan1_k<<<49, 1024, 0, stream>>>(cnt, part, bsum);
  scan2_k<<<1, 64, 0, stream>>>(bsum, boff);
  scan3_k<<<49, 1024, 0, stream>>>(part, boff, rs, cursor);
  fill_k<<<(E_ + 255) / 256, 256, 0, stream>>>(esrc, edst, cursor, sorted_src);
  gather_ln_k<<<N_ / 4, 256, 0, stream>>>(xb, rs, sorted_src,
                                          sn_g, sn_b, nn_g, nn_b, h);
  dim3 g1((TOK + 127) / 128, 2);
  gemm1_k<<<g1, 256, 0, stream>>>(h, W1t, b1, h1, TOK);
  gemm2_k<<<(TOK + 127) / 128, 256, 0, stream>>>(h1, W2t, b2, x, (float*)d_out, TOK);
}

// Round 8
// 347.857 us; speedup vs baseline: 1.2769x; 1.0992x over previous
//
#include <hip/hip_runtime.h>
#include <cstdint>

#define B_ 2
#define N_ 50000
#define D_ 128
#define E_ 800000
#define TOK 100000   // B_*N_

typedef __bf16 bf16x8 __attribute__((ext_vector_type(8)));
typedef float f32x4 __attribute__((ext_vector_type(4)));

__device__ __forceinline__ unsigned short f2bf(float f) {
  union { float f; uint32_t u; } v; v.f = f;
  uint32_t u = v.u;
  return (unsigned short)((u + 0x7FFFu + ((u >> 16) & 1u)) >> 16);
}
__device__ __forceinline__ float uasf(uint32_t u) {
  union { uint32_t u; float f; } v; v.u = u; return v.f;
}
// tanh-form GELU: v * sigmoid(1.5958*(v + 0.044715 v^3)); max |err| vs exact
// erf-GELU ~3e-4 << bf16 rounding of h1. Branch-free saturation.
__device__ __forceinline__ float fast_gelu(float v) {
  float p = v * (1.5957691f + 0.07135481f * v * v);
  return v * __builtin_amdgcn_rcpf(1.0f + __expf(-p));
}

// ---- fused prep: xb build (blocks 0..12499), W transpose (12500..12883),
// ---- dst histogram (12884..16008) ------------------------------------------
__global__ __launch_bounds__(256) void prep_k(
    const float* __restrict__ x, const float* __restrict__ W1,
    const float* __restrict__ W2, const int* __restrict__ edst,
    unsigned short* __restrict__ xb, unsigned short* __restrict__ W1t,
    unsigned short* __restrict__ W2t, int* __restrict__ cnt) {
  const int blk = blockIdx.x;
  if (blk < 12500) {               // x -> batch-interleaved bf16 xb[node][2][128]
    int q = (blk * 256 + threadIdx.x) * 4;
    int node = q >> 8;
    int rem = q & 255;
    int b = rem >> 7, c = rem & 127;
    float4 v = *(const float4*)(x + (size_t)b * (N_ * D_) + node * 128 + c);
    uint2 p = { (uint32_t)f2bf(v.x) | ((uint32_t)f2bf(v.y) << 16),
                (uint32_t)f2bf(v.z) | ((uint32_t)f2bf(v.w) << 16) };
    *(uint2*)(xb + q) = p;
  } else if (blk < 12884) {        // weight transpose to bf16 [n][k]
    int t = (blk - 12500) * 256 + threadIdx.x;
    if (t < 65536) {
      int n = t >> 8, k = t & 255;
      W1t[t] = f2bf(W1[k * 256 + n]);
    } else {
      int t2 = t - 65536;
      int n = t2 >> 8, k = t2 & 255;
      W2t[t2] = f2bf(W2[k * 128 + n]);
    }
  } else {                         // histogram of edge_dst
    int e = (blk - 12884) * 256 + threadIdx.x;
    if (e < E_) atomicAdd(&cnt[edst[e]], 1);
  }
}

// ---------------- hierarchical scan: phase 1 (block-local) ------------------
__global__ __launch_bounds__(1024) void scan1_k(const int* __restrict__ cnt,
                                                int* __restrict__ part,
                                                int* __restrict__ bsum) {
  __shared__ int wsum[16], woff[16];
  const int tid = threadIdx.x, lane = tid & 63, wv = tid >> 6;
  int i = blockIdx.x * 1024 + tid;
  int v = (i < N_) ? cnt[i] : 0;
  int s = v;
#pragma unroll
  for (int off = 1; off < 64; off <<= 1) {
    int t = __shfl_up(s, off);
    if (lane >= off) s += t;
  }
  if (lane == 63) wsum[wv] = s;
  __syncthreads();
  if (tid == 0) {
    int a = 0;
#pragma unroll
    for (int w = 0; w < 16; ++w) { woff[w] = a; a += wsum[w]; }
    bsum[blockIdx.x] = a;
  }
  __syncthreads();
  if (i < N_) part[i] = woff[wv] + s - v;
}

// ---------------- phase 2: scan the 49 block sums (one wave) ----------------
__global__ __launch_bounds__(64) void scan2_k(const int* __restrict__ bsum,
                                              int* __restrict__ boff) {
  int lane = threadIdx.x;
  int v = (lane < 49) ? bsum[lane] : 0;
  int s = v;
#pragma unroll
  for (int off = 1; off < 64; off <<= 1) {
    int t = __shfl_up(s, off);
    if (lane >= off) s += t;
  }
  boff[lane] = s - v;
}

// ---------------- phase 3: add block offsets, write rs + cursor -------------
__global__ __launch_bounds__(1024) void scan3_k(const int* __restrict__ part,
                                                const int* __restrict__ boff,
                                                int* __restrict__ rs,
                                                int* __restrict__ cursor) {
  int i = blockIdx.x * 1024 + threadIdx.x;
  if (i < N_) {
    int v = part[i] + boff[blockIdx.x];
    rs[i] = v; cursor[i] = v;
  }
  if (i == 0) rs[N_] = E_;
}

// ---------------- CSR build: counting-sort edge srcs by dst -----------------
__global__ __launch_bounds__(256) void fill_k(const int* __restrict__ esrc,
                                              const int* __restrict__ edst,
                                              int* __restrict__ cursor,
                                              int* __restrict__ sorted_src) {
  int e = blockIdx.x * 256 + threadIdx.x;
  if (e < E_) {
    int pos = atomicAdd(&cursor[edst[e]], 1);
    sorted_src[pos] = esrc[e];
  }
}

// ---------------- fused gather + dual LayerNorm -> h = [LN(x), LN(nb)] -----
__global__ __launch_bounds__(256) void gather_ln_k(
    const unsigned short* __restrict__ xb,
    const int* __restrict__ rs, const int* __restrict__ ss,
    const float* __restrict__ sn_g, const float* __restrict__ sn_b,
    const float* __restrict__ nn_g, const float* __restrict__ nn_b,
    unsigned short* __restrict__ h) {
  const int node = blockIdx.x * 4 + (threadIdx.x >> 6);   // grid exact: 50000
  const int lane = threadIdx.x & 63;
  const int half = lane >> 5;        // batch index
  const int l32 = lane & 31;
  const int c = l32 * 4;
  const int r0 = rs[node], r1 = rs[node + 1];
  const unsigned short* xrow = xb + lane * 4;
  float a0 = 0.f, a1 = 0.f, a2 = 0.f, a3 = 0.f;
  for (int e = r0; e < r1; e += 16) {
    int idx[16];
#pragma unroll
    for (int j = 0; j < 16; ++j) {
      int ej = e + j;
      idx[j] = ss[(ej < r1) ? ej : r0];
    }
    uint2 v[16];
#pragma unroll
    for (int j = 0; j < 16; ++j)
      v[j] = *(const uint2*)(xrow + (size_t)idx[j] * 256);
#pragma unroll
    for (int j = 0; j < 16; ++j) {
      if (e + j < r1) {
        a0 += uasf(v[j].x << 16); a1 += uasf(v[j].x & 0xffff0000u);
        a2 += uasf(v[j].y << 16); a3 += uasf(v[j].y & 0xffff0000u);
      }
    }
  }
  const float invd = 1.0f / fmaxf((float)(r1 - r0), 1.0f);
  float n0 = a0 * invd, n1 = a1 * invd, n2 = a2 * invd, n3 = a3 * invd;
  uint2 xq = *(const uint2*)(xrow + (size_t)node * 256);  // own row (bf16)
  float x0 = uasf(xq.x << 16), x1 = uasf(xq.x & 0xffff0000u);
  float x2 = uasf(xq.y << 16), x3 = uasf(xq.y & 0xffff0000u);
  float sx = (x0 + x1) + (x2 + x3);
  float sxx = (x0 * x0 + x1 * x1) + (x2 * x2 + x3 * x3);
  float sn = (n0 + n1) + (n2 + n3);
  float snn = (n0 * n0 + n1 * n1) + (n2 * n2 + n3 * n3);
#pragma unroll
  for (int off = 1; off < 32; off <<= 1) {   // stays within the 32-lane half
    sx  += __shfl_xor(sx, off);  sxx += __shfl_xor(sxx, off);
    sn  += __shfl_xor(sn, off);  snn += __shfl_xor(snn, off);
  }
  const float r = 1.0f / 128.0f;
  float mx = sx * r, vx = fmaxf(sxx * r - mx * mx, 0.f);
  float mn = sn * r, vn = fmaxf(snn * r - mn * mn, 0.f);
  float rx = rsqrtf(vx + 1e-5f), rn = rsqrtf(vn + 1e-5f);
  float4 g1v = *(const float4*)(sn_g + c), b1v = *(const float4*)(sn_b + c);
  float4 g2v = *(const float4*)(nn_g + c), b2v = *(const float4*)(nn_b + c);
  float y0 = (x0 - mx) * rx * g1v.x + b1v.x;
  float y1 = (x1 - mx) * rx * g1v.y + b1v.y;
  float y2 = (x2 - mx) * rx * g1v.z + b1v.z;
  float y3 = (x3 - mx) * rx * g1v.w + b1v.w;
  float z0 = (n0 - mn) * rn * g2v.x + b2v.x;
  float z1 = (n1 - mn) * rn * g2v.y + b2v.y;
  float z2 = (n2 - mn) * rn * g2v.z + b2v.z;
  float z3 = (n3 - mn) * rn * g2v.w + b2v.w;
  unsigned short* hr = h + ((size_t)half * N_ + node) * 256;
  uint2 py = { (uint32_t)f2bf(y0) | ((uint32_t)f2bf(y1) << 16),
               (uint32_t)f2bf(y2) | ((uint32_t)f2bf(y3) << 16) };
  uint2 pz = { (uint32_t)f2bf(z0) | ((uint32_t)f2bf(z1) << 16),
               (uint32_t)f2bf(z2) | ((uint32_t)f2bf(z3) << 16) };
  *(uint2*)(hr + c)       = py;
  *(uint2*)(hr + 128 + c) = pz;
}

// ---------------- GEMM1: h1 = GELU(h @ W1t^T + b1), tile 128x128 (y=2) ------
__global__ __launch_bounds__(256, 4) void gemm1_k(
    const unsigned short* __restrict__ A,
    const unsigned short* __restrict__ Wt,
    const float* __restrict__ bias,
    unsigned short* __restrict__ outp, int M) {
  constexpr int LDA = 72;
  __shared__ unsigned short As[128 * LDA];
  __shared__ unsigned short Bs[128 * LDA];
  const int tid = threadIdx.x;
  const int wave = tid >> 6, lane = tid & 63;
  const int wr = wave >> 1, wc = wave & 1;
  const int quad = lane >> 4, l15 = lane & 15;
  const int m0 = blockIdx.x * 128, n0 = blockIdx.y * 128;
  f32x4 acc[4][4] = {};
  for (int kb = 0; kb < 256; kb += 64) {
#pragma unroll
    for (int c = 0; c < 4; ++c) {
      int idx = c * 256 + tid;
      int row = idx >> 3, c8 = (idx & 7) << 3;
      int gm = m0 + row;
      uint4 va = {0u, 0u, 0u, 0u};
      if (gm < M) va = *(const uint4*)(A + (size_t)gm * 256 + kb + c8);
      *(uint4*)(&As[row * LDA + c8]) = va;
      uint4 vb = *(const uint4*)(Wt + (size_t)(n0 + row) * 256 + kb + c8);
      *(uint4*)(&Bs[row * LDA + c8]) = vb;
    }
    __syncthreads();
#pragma unroll
    for (int kc = 0; kc < 64; kc += 32) {
      bf16x8 a[4], b[4];
#pragma unroll
      for (int i = 0; i < 4; ++i) {
        a[i] = *(const bf16x8*)(&As[(wr * 64 + i * 16 + l15) * LDA + kc + quad * 8]);
        b[i] = *(const bf16x8*)(&Bs[(wc * 64 + i * 16 + l15) * LDA + kc + quad * 8]);
      }
#pragma unroll
      for (int mi = 0; mi < 4; ++mi)
#pragma unroll
        for (int ni = 0; ni < 4; ++ni)
          acc[mi][ni] = __builtin_amdgcn_mfma_f32_16x16x32_bf16(a[mi], b[ni], acc[mi][ni], 0, 0, 0);
    }
    __syncthreads();
  }
#pragma unroll
  for (int mi = 0; mi < 4; ++mi) {
#pragma unroll
    for (int ni = 0; ni < 4; ++ni) {
      int col = n0 + wc * 64 + ni * 16 + l15;
      float bv = bias[col];
#pragma unroll
      for (int rr = 0; rr < 4; ++rr) {
        int row = m0 + wr * 64 + mi * 16 + quad * 4 + rr;
        if (row < M) {
          float v = fast_gelu(acc[mi][ni][rr] + bv);
          outp[(size_t)row * 256 + col] = f2bf(v);
        }
      }
    }
  }
}

// ---------------- GEMM2: out = h1 @ W2t^T + b2 + x (fp32 out) ---------------
__global__ __launch_bounds__(256, 4) void gemm2_k(
    const unsigned short* __restrict__ A,
    const unsigned short* __restrict__ Wt,
    const float* __restrict__ bias,
    const float* __restrict__ resid,
    float* __restrict__ outp, int M) {
  constexpr int LDA = 72;
  __shared__ unsigned short As[128 * LDA];
  __shared__ unsigned short Bs[128 * LDA];
  const int tid = threadIdx.x;
  const int wave = tid >> 6, lane = tid & 63;
  const int wr = wave >> 1, wc = wave & 1;
  const int quad = lane >> 4, l15 = lane & 15;
  const int m0 = blockIdx.x * 128;
  f32x4 acc[4][4] = {};
  for (int kb = 0; kb < 256; kb += 64) {
#pragma unroll
    for (int c = 0; c < 4; ++c) {
      int idx = c * 256 + tid;
      int row = idx >> 3, c8 = (idx & 7) << 3;
      int gm = m0 + row;
      uint4 va = {0u, 0u, 0u, 0u};
      if (gm < M) va = *(const uint4*)(A + (size_t)gm * 256 + kb + c8);
      *(uint4*)(&As[row * LDA + c8]) = va;
      uint4 vb = *(const uint4*)(Wt + (size_t)row * 256 + kb + c8);
      *(uint4*)(&Bs[row * LDA + c8]) = vb;
    }
    __syncthreads();
#pragma unroll
    for (int kc = 0; kc < 64; kc += 32) {
      bf16x8 a[4], b[4];
#pragma unroll
      for (int i = 0; i < 4; ++i) {
        a[i] = *(const bf16x8*)(&As[(wr * 64 + i * 16 + l15) * LDA + kc + quad * 8]);
        b[i] = *(const bf16x8*)(&Bs[(wc * 64 + i * 16 + l15) * LDA + kc + quad * 8]);
      }
#pragma unroll
      for (int mi = 0; mi < 4; ++mi)
#pragma unroll
        for (int ni = 0; ni < 4; ++ni)
          acc[mi][ni] = __builtin_amdgcn_mfma_f32_16x16x32_bf16(a[mi], b[ni], acc[mi][ni], 0, 0, 0);
    }
    __syncthreads();
  }
#pragma unroll
  for (int mi = 0; mi < 4; ++mi) {
#pragma unroll
    for (int ni = 0; ni < 4; ++ni) {
      int col = wc * 64 + ni * 16 + l15;
      float bv = bias[col];
#pragma unroll
      for (int rr = 0; rr < 4; ++rr) {
        int row = m0 + wr * 64 + mi * 16 + quad * 4 + rr;
        if (row < M) {
          float v = acc[mi][ni][rr] + bv + resid[(size_t)row * 128 + col];
          outp[(size_t)row * 128 + col] = v;
        }
      }
    }
  }
}

extern "C" void kernel_launch(void* const* d_in, const int* in_sizes, int n_in,
                              void* d_out, int out_size, void* d_ws, size_t ws_size,
                              hipStream_t stream) {
  const float* x    = (const float*)d_in[0];
  const int* esrc   = (const int*)d_in[1];
  const int* edst   = (const int*)d_in[2];
  const float* sn_g = (const float*)d_in[4];
  const float* sn_b = (const float*)d_in[5];
  const float* nn_g = (const float*)d_in[6];
  const float* nn_b = (const float*)d_in[7];
  const float* W1   = (const float*)d_in[8];
  const float* b1   = (const float*)d_in[9];
  const float* W2   = (const float*)d_in[10];
  const float* b2   = (const float*)d_in[11];

  char* ws = (char*)d_ws;
  const size_t H_BYTES = (size_t)TOK * 256 * 2;          // 51.2 MB
  unsigned short* h = (unsigned short*)ws;               // [TOK][256] bf16
  // CSR + xb region (dead before gemm1), aliased by h1:
  char* csr = ws + H_BYTES;
  int* cnt        = (int*)(csr);                          // 50000 ints
  int* part       = (int*)(csr + 200000);                 // 50000 ints
  int* rs         = (int*)(csr + 400000);                 // 50001 ints
  int* cursor     = (int*)(csr + 600016);                 // 50000 ints
  int* bsum       = (int*)(csr + 800016);                 // 49 ints
  int* boff       = (int*)(csr + 800224);                 // 64 ints
  int* sorted_src = (int*)(csr + 800512);                 // 800000 ints -> ends 4,000,512
  unsigned short* xb = (unsigned short*)(csr + 4194304);  // [N][2][128] bf16, 25.6 MB
  unsigned short* h1 = (unsigned short*)(ws + H_BYTES);   // aliases CSR+xb after gather
  unsigned short* W1t = (unsigned short*)(ws + 2 * H_BYTES);
  unsigned short* W2t = W1t + 65536;

  hipMemsetAsync(cnt, 0, (size_t)N_ * sizeof(int), stream);
  prep_k<<<16009, 256, 0, stream>>>(x, W1, W2, edst, xb, W1t, W2t, cnt);
  scan1_k<<<49, 1024, 0, stream>>>(cnt, part, bsum);
  scan2_k<<<1, 64, 0, stream>>>(bsum, boff);
  scan3_k<<<49, 1024, 0, stream>>>(part, boff, rs, cursor);
  fill_k<<<(E_ + 255) / 256, 256, 0, stream>>>(esrc, edst, cursor, sorted_src);
  gather_ln_k<<<N_ / 4, 256, 0, stream>>>(xb, rs, sorted_src,
                                          sn_g, sn_b, nn_g, nn_b, h);
  dim3 g1((TOK + 127) / 128, 2);
  gemm1_k<<<g1, 256, 0, stream>>>(h, W1t, b1, h1, TOK);
  gemm2_k<<<(TOK + 127) / 128, 256, 0, stream>>>(h1, W2t, b2, x, (float*)d_out, TOK);
}